// Round 11
// baseline (359.345 us; speedup 1.0000x reference)
//
#include <hip/hip_runtime.h>
#include <math.h>

#define HDIM 128
#define CH 4096                 // edges per partition chunk
typedef unsigned int uint;
using short8 = __attribute__((ext_vector_type(8))) short;
using f32x4  = __attribute__((ext_vector_type(4))) float;

__device__ __forceinline__ uint pack_bf16x2(float a, float b) {
    uint ua = __float_as_uint(a), ub = __float_as_uint(b);
    ua = (ua + 0x7fffu + ((ua >> 16) & 1u)) >> 16;
    ub = (ub + 0x7fffu + ((ub >> 16) & 1u)) & 0xffff0000u;
    return ua | ub;
}
__device__ __forceinline__ unsigned short pack_bf16(float a) {
    uint ua = __float_as_uint(a);
    return (unsigned short)((ua + 0x7fffu + ((ua >> 16) & 1u)) >> 16);
}

// ---- prep: h->hb bf16 SLICE-major (4 slices x 32 dims), W->Wt bf16 ---------
__global__ __launch_bounds__(256) void prep_kernel(
    const float* __restrict__ h, uint* __restrict__ hb, int n_nodes,
    const float* __restrict__ W0, const float* __restrict__ W1,
    unsigned short* __restrict__ Wt0, unsigned short* __restrict__ Wt1)
{
    const int N16 = n_nodes * 16;          // uints per slice
    const int t0 = n_nodes * 64;           // hb uints total
    const int total = t0 + 2 * 32768;
    for (int i = blockIdx.x * 256 + threadIdx.x; i < total; i += gridDim.x * 256) {
        if (i < t0) {
            int s = i / N16;
            int r = i - s * N16;
            int n = r >> 4, q = r & 15;     // q = dim-pair within slice
            float2 v = reinterpret_cast<const float2*>(h)[(size_t)n * 64 + s * 16 + q];
            hb[i] = pack_bf16x2(v.x, v.y);
        } else {
            int t = i - t0;
            const float* W = (t < 32768) ? W0 : W1;
            unsigned short* Wt = (t < 32768) ? Wt0 : Wt1;
            int j = t & 32767;
            int c = j >> 8, k = j & 255;
            Wt[j] = pack_bf16(W[k * HDIM + c]);
        }
    }
}

// ---- per-chunk bucket histogram via LDS (zero global atomics) --------------
__global__ __launch_bounds__(256) void histc_kernel(
    const int* __restrict__ dst_ct, int* __restrict__ cntm_ct, int n_ct, int nv_ct,
    const int* __restrict__ dst_cb, int* __restrict__ cntm_cb, int n_cb, int nv_cb,
    int nbuckets)
{
    __shared__ int lh[512];
    const bool cb = ((int)blockIdx.x >= nv_ct);
    const int vb = cb ? blockIdx.x - nv_ct : blockIdx.x;
    const int* dst = cb ? dst_cb : dst_ct;
    int* cntm      = cb ? cntm_cb : cntm_ct;
    const int n  = cb ? n_cb : n_ct;
    const int NV = cb ? nv_cb : nv_ct;
    for (int j = threadIdx.x; j < 512; j += 256) lh[j] = 0;
    __syncthreads();
    const int e0 = vb << 12;
    const int e1 = min(n, e0 + CH);
    for (int i = e0 + threadIdx.x; i < e1; i += 256)
        atomicAdd(&lh[dst[i] >> 7], 1);
    __syncthreads();
    for (int j = threadIdx.x; j < nbuckets; j += 256)
        cntm[j * NV + vb] = lh[j];
}

// ---- scanA: within-bucket exclusive scan of chunk counts + bucket totals ---
__global__ __launch_bounds__(256) void scanA_kernel(
    int* __restrict__ cntm_ct, int* __restrict__ tot_ct, int nv_ct,
    int* __restrict__ cntm_cb, int* __restrict__ tot_cb, int nv_cb,
    int nbuckets)
{
    __shared__ int buf[256];
    const bool cb = ((int)blockIdx.x >= nbuckets);
    const int b = cb ? blockIdx.x - nbuckets : blockIdx.x;
    int* cntm = cb ? cntm_cb : cntm_ct;
    int* tot  = cb ? tot_cb : tot_ct;
    const int NV = cb ? nv_cb : nv_ct;
    const int t = threadIdx.x;
    int base = 0;
    for (int t0 = 0; t0 < NV; t0 += 256) {
        const int idx = t0 + t;
        const int v = (idx < NV) ? cntm[b * NV + idx] : 0;
        buf[t] = v;
        __syncthreads();
        #pragma unroll
        for (int off = 1; off < 256; off <<= 1) {
            int x = (t >= off) ? buf[t - off] : 0;
            __syncthreads();
            buf[t] += x;
            __syncthreads();
        }
        if (idx < NV) cntm[b * NV + idx] = base + buf[t] - v;   // exclusive
        base += buf[255];
        __syncthreads();
    }
    if (t == 0) tot[b] = base;
}

// ---- scanB: scan bucket totals -> bucket base offsets (incl. grand total) --
__global__ __launch_bounds__(1024) void scanB_kernel(
    const int* __restrict__ tot_ct, int* __restrict__ bkt_ct,
    const int* __restrict__ tot_cb, int* __restrict__ bkt_cb, int nbuckets)
{
    __shared__ int buf[1024];
    const int* tot = blockIdx.x ? tot_cb : tot_ct;
    int* bkt       = blockIdx.x ? bkt_cb : bkt_ct;
    const int t = threadIdx.x;
    const int v = (t < nbuckets) ? tot[t] : 0;
    buf[t] = v;
    __syncthreads();
    #pragma unroll
    for (int off = 1; off < 1024; off <<= 1) {
        int x = (t >= off) ? buf[t - off] : 0;
        __syncthreads();
        buf[t] += x;
        __syncthreads();
    }
    if (t < nbuckets) bkt[t] = buf[t] - v;
    if (t == nbuckets - 1) bkt[nbuckets] = buf[t];
}

// ---- stage 1: partition edges into 128-node buckets (LDS cursors) ----------
__global__ __launch_bounds__(256) void part_kernel(
    const int* __restrict__ dst_ct, const int* __restrict__ src_ct,
    const float* __restrict__ feat_ct, const int* __restrict__ off_ct,
    const int* __restrict__ bkt_ct, int2* __restrict__ ebkt_ct, int n_ct, int nv_ct,
    const int* __restrict__ dst_cb, const int* __restrict__ src_cb,
    const float* __restrict__ feat_cb, const int* __restrict__ off_cb,
    const int* __restrict__ bkt_cb, int2* __restrict__ ebkt_cb, int n_cb, int nv_cb,
    int nbuckets)
{
    __shared__ int cur[512];
    const bool cb = ((int)blockIdx.x >= nv_ct);
    const int vb = cb ? blockIdx.x - nv_ct : blockIdx.x;
    const int* dst    = cb ? dst_cb : dst_ct;
    const int* srcp   = cb ? src_cb : src_ct;
    const float* feat = cb ? feat_cb : feat_ct;
    const int* off    = cb ? off_cb : off_ct;
    const int* bkt    = cb ? bkt_cb : bkt_ct;
    int2* ebkt        = cb ? ebkt_cb : ebkt_ct;
    const int n  = cb ? n_cb : n_ct;
    const int NV = cb ? nv_cb : nv_ct;
    for (int j = threadIdx.x; j < nbuckets; j += 256)
        cur[j] = off[j * NV + vb] + bkt[j];
    __syncthreads();
    const int e0 = vb << 12;
    const int e1 = min(n, e0 + CH);
    for (int i = e0 + threadIdx.x; i < e1; i += 256) {
        int d = dst[i];
        int p = atomicAdd(&cur[d >> 7], 1);
        ebkt[p] = make_int2((srcp[i] & 0xFFFF) | ((d & 127) << 16),
                            __float_as_int(feat[i]));
    }
}

// ---- stage 2: within-bucket CSR sort + per-node counts + rowptr ------------
__global__ __launch_bounds__(256) void sortb_kernel(
    const int2* __restrict__ ebkt_ct, const int* __restrict__ bkt_ct,
    const int2* __restrict__ ebkt_cb, const int* __restrict__ bkt_cb,
    int2* __restrict__ ecsr_ct, int2* __restrict__ ecsr_cb,
    int* __restrict__ rowptr_ct, int* __restrict__ rowptr_cb,
    int n_nodes, int nbuckets)
{
    __shared__ int cnt[128];
    __shared__ int pref[128];
    const int b = blockIdx.x >> 1;
    const bool cb = blockIdx.x & 1;
    const int2* ebkt = cb ? ebkt_cb : ebkt_ct;
    const int* bkt   = cb ? bkt_cb : bkt_ct;
    int2* ecsr       = cb ? ecsr_cb : ecsr_ct;
    int* rowptr      = cb ? rowptr_cb : rowptr_ct;
    const int t = threadIdx.x;
    const int beg = bkt[b], end = bkt[b + 1];

    if (t < 128) cnt[t] = 0;
    __syncthreads();
    for (int i = beg + t; i < end; i += 256)
        atomicAdd(&cnt[((uint)ebkt[i].x) >> 16], 1);
    __syncthreads();
    if (t < 128) pref[t] = cnt[t];
    __syncthreads();
    #pragma unroll
    for (int off = 1; off < 128; off <<= 1) {
        int v = 0;
        if (t < 128 && t >= off) v = pref[t - off];
        __syncthreads();
        if (t < 128) pref[t] += v;
        __syncthreads();
    }
    if (t < 128) {
        int n0 = b * 128;
        int base = beg + pref[t] - cnt[t];
        if (n0 + t < n_nodes) rowptr[n0 + t] = base;
        cnt[t] = base;            // reuse as running cursor
    }
    if (b == nbuckets - 1 && t == 0) rowptr[n_nodes] = end;
    __syncthreads();
    for (int i = beg + t; i < end; i += 256) {
        int2 r = ebkt[i];
        int d = ((uint)r.x) >> 16;
        int p = atomicAdd(&cnt[d], 1);
        ecsr[p] = r;
    }
}

// ------ Sliced gather: wave owns (type, node, slice of 32 dims) -------------
// slice = blockIdx&3 rides the 8-XCD round-robin -> each XCD touches one
// 3.2MB h-slice (L2-resident). 8 edges in flight x 8 lanes x uint2; register
// accumulate; reduce via shfl_xor(8/16/32); lanes 0-7 write one 64B sector.
__global__ __launch_bounds__(256) void csr_gather_bf16_kernel(
    const uint2* __restrict__ hb,
    const int* __restrict__ rp_ct, const int2* __restrict__ e_ct,
    const int* __restrict__ rp_cb, const int2* __restrict__ e_cb,
    uint2* __restrict__ mct, uint2* __restrict__ mcb, int n_nodes)
{
    const int lane = threadIdx.x & 63;
    const int eg = lane >> 3;        // edge group 0..7
    const int q  = lane & 7;         // uint2 slot within the 32-dim slice
    const int slice = blockIdx.x & 3;
    const int wid = threadIdx.x >> 6;
    const int u0 = (blockIdx.x >> 2) * 4 + wid;
    const int ustride = (gridDim.x >> 2) * 4;
    const uint2* hbs = hb + (size_t)slice * ((size_t)n_nodes * 8);
    const int total = 2 * n_nodes;
    for (int v = u0; v < total; v += ustride) {
        const bool cbt = (v >= n_nodes);
        const int n = cbt ? (v - n_nodes) : v;
        const int* rp    = cbt ? rp_cb : rp_ct;
        const int2* ecsr = cbt ? e_cb : e_ct;
        uint2* m = cbt ? mcb : mct;
        const int beg = rp[n], end = rp[n + 1];
        float a0 = 0.f, a1 = 0.f, a2 = 0.f, a3 = 0.f;
        for (int i0 = beg; i0 < end; i0 += 64) {
            const int cnt = min(64, end - i0);
            int s = 0; float f = 0.0f;
            if (lane < cnt) {
                int2 e = ecsr[i0 + lane];
                s = e.x & 0xFFFF;
                f = __int_as_float(e.y);
            }
            const int nsub = (cnt + 7) >> 3;
            #pragma unroll 4
            for (int jj = 0; jj < nsub; ++jj) {
                int idx = jj * 8 + eg;       // lanes >= cnt carry f=0 (safe)
                int   sj = __shfl(s, idx);
                float fj = __shfl(f, idx);
                uint2 hv = hbs[(size_t)sj * 8 + q];
                a0 = fmaf(fj, __uint_as_float(hv.x << 16),         a0);
                a1 = fmaf(fj, __uint_as_float(hv.x & 0xffff0000u), a1);
                a2 = fmaf(fj, __uint_as_float(hv.y << 16),         a2);
                a3 = fmaf(fj, __uint_as_float(hv.y & 0xffff0000u), a3);
            }
        }
        a0 += __shfl_xor(a0, 8);  a1 += __shfl_xor(a1, 8);
        a2 += __shfl_xor(a2, 8);  a3 += __shfl_xor(a3, 8);
        a0 += __shfl_xor(a0, 16); a1 += __shfl_xor(a1, 16);
        a2 += __shfl_xor(a2, 16); a3 += __shfl_xor(a3, 16);
        a0 += __shfl_xor(a0, 32); a1 += __shfl_xor(a1, 32);
        a2 += __shfl_xor(a2, 32); a3 += __shfl_xor(a3, 32);
        if (eg == 0)
            m[(size_t)n * 32 + slice * 8 + q] =
                make_uint2(pack_bf16x2(a0, a1), pack_bf16x2(a2, a3));
    }
}

// -------- Zero-LDS MFMA GEMM: wave owns 32 rows x all 128 cols --------------
__global__ __launch_bounds__(256) void gemm_mfma_kernel(
    const unsigned short* __restrict__ mct, const unsigned short* __restrict__ mcb,
    const unsigned short* __restrict__ Wt, const float* __restrict__ bias,
    const float* __restrict__ h_in, float* __restrict__ h_out,
    unsigned short* __restrict__ hb_out, int n_nodes, int write_hb)
{
    const int base = blockIdx.x * 128;
    const int lane = threadIdx.x & 63;
    const int wid  = threadIdx.x >> 6;
    const int lr = lane & 15, lg = lane >> 4;
    const int row0 = base + wid * 32;

    f32x4 acc[2][8];
    #pragma unroll
    for (int mi = 0; mi < 2; ++mi)
        #pragma unroll
        for (int ni = 0; ni < 8; ++ni)
            acc[mi][ni] = (f32x4){0.f, 0.f, 0.f, 0.f};

    const int last = (base + 128 > n_nodes);

    #pragma unroll
    for (int ks = 0; ks < 8; ++ks) {
        const int koff = ks * 32 + lg * 8;
        short8 a[2], b[8];
        #pragma unroll
        for (int mi = 0; mi < 2; ++mi) {
            int node = row0 + mi * 16 + lr;
            if (last && node >= n_nodes) node = n_nodes - 1;
            const unsigned short* srcp = (koff < 128)
                ? (mct + (size_t)node * HDIM + koff)
                : (mcb + (size_t)node * HDIM + (koff - 128));
            a[mi] = *reinterpret_cast<const short8*>(srcp);
        }
        #pragma unroll
        for (int ni = 0; ni < 8; ++ni) {
            int col = ni * 16 + lr;
            b[ni] = *reinterpret_cast<const short8*>(Wt + (size_t)col * 256 + koff);
        }
        #pragma unroll
        for (int mi = 0; mi < 2; ++mi)
            #pragma unroll
            for (int ni = 0; ni < 8; ++ni)
                acc[mi][ni] = __builtin_amdgcn_mfma_f32_16x16x32_bf16(
                    a[mi], b[ni], acc[mi][ni], 0, 0, 0);
    }

    #pragma unroll
    for (int mi = 0; mi < 2; ++mi) {
        #pragma unroll
        for (int ni = 0; ni < 8; ++ni) {
            const int col = ni * 16 + lr;
            const float bc = bias[col];
            #pragma unroll
            for (int j = 0; j < 4; ++j) {
                int node = row0 + mi * 16 + lg * 4 + j;
                if (node < n_nodes) {
                    float x = acc[mi][ni][j] + bc;
                    float g = 0.5f * x * (1.0f + erff(x * 0.70710678118654752f));
                    float o = h_in[(size_t)node * HDIM + col] + g;
                    h_out[(size_t)node * HDIM + col] = o;
                    if (write_hb) {
                        // slice-major hb: slice = col>>5, within-slice dim = col&31
                        hb_out[(size_t)(col >> 5) * ((size_t)n_nodes * 32)
                               + (size_t)node * 32 + (col & 31)] = pack_bf16(o);
                    }
                }
            }
        }
    }
}

// ---------------- Fallback path kernels (ws too small / big graphs) ---------
__global__ __launch_bounds__(256) void edge_agg_kernel(
    const float* __restrict__ h, const float* __restrict__ feat,
    const int* __restrict__ src, const int* __restrict__ dst,
    float* __restrict__ m, int n_edges)
{
    long long tid = (long long)blockIdx.x * 256 + threadIdx.x;
    int e = (int)(tid >> 5);
    if (e >= n_edges) return;
    int q = (int)(tid & 31);
    float f = feat[e];
    size_t s = (size_t)src[e] * HDIM;
    size_t d = (size_t)dst[e] * HDIM;
    float4 v = reinterpret_cast<const float4*>(h + s)[q];
    float* mp = m + d + (size_t)q * 4;
    unsafeAtomicAdd(mp + 0, f * v.x);
    unsafeAtomicAdd(mp + 1, f * v.y);
    unsafeAtomicAdd(mp + 2, f * v.z);
    unsafeAtomicAdd(mp + 3, f * v.w);
}

__global__ __launch_bounds__(256) void gemm_gelu_res_kernel(
    const float* __restrict__ mct, const float* __restrict__ mcb,
    const float* __restrict__ W, const float* __restrict__ bias,
    const float* __restrict__ h_in, float* __restrict__ h_out, int n_nodes)
{
    __shared__ float Wl[256 * HDIM];
    __shared__ float trow[8][2 * HDIM];
    for (int i = threadIdx.x; i < 256 * HDIM; i += 256)
        Wl[i] = W[i];
    const int c = threadIdx.x & 127;
    const int g = threadIdx.x >> 7;
    const float bc = bias[c];
    __syncthreads();
    const int niter = (n_nodes + 7) >> 3;
    for (int it = blockIdx.x; it < niter; it += gridDim.x) {
        __syncthreads();
        for (int j = threadIdx.x; j < 8 * 256; j += 256) {
            int nn = j >> 8;
            int k  = j & 255;
            long long node = (long long)it * 8 + nn;
            float val = 0.0f;
            if (node < n_nodes)
                val = (k < HDIM) ? mct[node * HDIM + k]
                                 : mcb[node * HDIM + (k - HDIM)];
            trow[nn][k] = val;
        }
        __syncthreads();
        const float* t0 = trow[g * 4 + 0];
        const float* t1 = trow[g * 4 + 1];
        const float* t2 = trow[g * 4 + 2];
        const float* t3 = trow[g * 4 + 3];
        float a0 = bc, a1 = bc, a2 = bc, a3 = bc;
        #pragma unroll 8
        for (int k = 0; k < 256; ++k) {
            float w = Wl[k * HDIM + c];
            a0 = fmaf(t0[k], w, a0);
            a1 = fmaf(t1[k], w, a1);
            a2 = fmaf(t2[k], w, a2);
            a3 = fmaf(t3[k], w, a3);
        }
        float accs[4] = {a0, a1, a2, a3};
        #pragma unroll
        for (int j = 0; j < 4; ++j) {
            long long node = (long long)it * 8 + g * 4 + j;
            if (node < n_nodes) {
                float x = accs[j];
                float gl = 0.5f * x * (1.0f + erff(x * 0.70710678118654752f));
                h_out[node * HDIM + c] = h_in[node * HDIM + c] + gl;
            }
        }
    }
}

extern "C" void kernel_launch(void* const* d_in, const int* in_sizes, int n_in,
                              void* d_out, int out_size, void* d_ws, size_t ws_size,
                              hipStream_t stream)
{
    const float* h0      = (const float*)d_in[0];
    const float* feat_ct = (const float*)d_in[1];
    const float* feat_cb = (const float*)d_in[2];
    const int*   src_ct  = (const int*)d_in[3];
    const int*   dst_ct  = (const int*)d_in[4];
    const int*   src_cb  = (const int*)d_in[5];
    const int*   dst_cb  = (const int*)d_in[6];
    const float* W0      = (const float*)d_in[7];
    const float* b0      = (const float*)d_in[8];
    const float* W1      = (const float*)d_in[9];
    const float* b1      = (const float*)d_in[10];

    const int n_nodes    = in_sizes[0] / HDIM;
    const int n_edges_ct = in_sizes[3];
    const int n_edges_cb = in_sizes[5];
    float* out = (float*)d_out;

    const int nbuckets = (n_nodes + 127) >> 7;
    const int nv_ct = (n_edges_ct + CH - 1) / CH;
    const int nv_cb = (n_edges_cb + CH - 1) / CH;

    // ---- workspace layout (256B-aligned chunks) ----
    char* p = (char*)d_ws;
    auto take = [&](size_t bytes) -> char* {
        char* r = p;
        p += (bytes + 255) & ~(size_t)255;
        return r;
    };
    unsigned short* hb   = (unsigned short*)take((size_t)n_nodes * HDIM * 2);
    unsigned short* mctb = (unsigned short*)take((size_t)n_nodes * HDIM * 2);
    unsigned short* mcbb = (unsigned short*)take((size_t)n_nodes * HDIM * 2);
    unsigned short* Wt0  = (unsigned short*)take(32768 * 2);
    unsigned short* Wt1  = (unsigned short*)take(32768 * 2);
    int* cntm_ct = (int*)take((size_t)nbuckets * nv_ct * 4);
    int* cntm_cb = (int*)take((size_t)nbuckets * nv_cb * 4);
    int* tot_ct  = (int*)take((size_t)nbuckets * 4);
    int* tot_cb  = (int*)take((size_t)nbuckets * 4);
    int* bkt_ct  = (int*)take(((size_t)nbuckets + 1) * 4);
    int* bkt_cb  = (int*)take(((size_t)nbuckets + 1) * 4);
    int* rowptr_ct = (int*)take(((size_t)n_nodes + 1) * 4);
    int* rowptr_cb = (int*)take(((size_t)n_nodes + 1) * 4);
    int2* ecsr_ct = (int2*)take((size_t)n_edges_ct * 8);
    int2* ecsr_cb = (int2*)take((size_t)n_edges_cb * 8);
    const size_t need_bytes = (size_t)(p - (char*)d_ws);
    // bucket-partition scratch overlaps mctb/mcbb (dead before gather writes m)
    int2* ebkt_ct = (int2*)mctb;
    int2* ebkt_cb = (int2*)mcbb;

    const bool ebkt_fits =
        ((size_t)n_edges_ct * 8 <= (size_t)n_nodes * HDIM * 2) &&
        ((size_t)n_edges_cb * 8 <= (size_t)n_nodes * HDIM * 2);

    if (ws_size >= need_bytes && n_nodes <= 65536 && ebkt_fits) {
        prep_kernel<<<2048, 256, 0, stream>>>(
            h0, (uint*)hb, n_nodes, W0, W1, Wt0, Wt1);
        histc_kernel<<<nv_ct + nv_cb, 256, 0, stream>>>(
            dst_ct, cntm_ct, n_edges_ct, nv_ct,
            dst_cb, cntm_cb, n_edges_cb, nv_cb, nbuckets);
        scanA_kernel<<<nbuckets * 2, 256, 0, stream>>>(
            cntm_ct, tot_ct, nv_ct, cntm_cb, tot_cb, nv_cb, nbuckets);
        scanB_kernel<<<2, 1024, 0, stream>>>(
            tot_ct, bkt_ct, tot_cb, bkt_cb, nbuckets);
        part_kernel<<<nv_ct + nv_cb, 256, 0, stream>>>(
            dst_ct, src_ct, feat_ct, cntm_ct, bkt_ct, ebkt_ct, n_edges_ct, nv_ct,
            dst_cb, src_cb, feat_cb, cntm_cb, bkt_cb, ebkt_cb, n_edges_cb, nv_cb,
            nbuckets);
        sortb_kernel<<<nbuckets * 2, 256, 0, stream>>>(
            ebkt_ct, bkt_ct, ebkt_cb, bkt_cb, ecsr_ct, ecsr_cb,
            rowptr_ct, rowptr_cb, n_nodes, nbuckets);
        const int gemm_blocks = (n_nodes + 127) / 128;
        const float* hin = h0;
        for (int layer = 0; layer < 2; ++layer) {
            csr_gather_bf16_kernel<<<2048, 256, 0, stream>>>(
                (const uint2*)hb, rowptr_ct, ecsr_ct, rowptr_cb, ecsr_cb,
                (uint2*)mctb, (uint2*)mcbb, n_nodes);
            gemm_mfma_kernel<<<gemm_blocks, 256, 0, stream>>>(
                mctb, mcbb, layer ? Wt1 : Wt0, layer ? b1 : b0,
                hin, out, hb, n_nodes, layer == 0 ? 1 : 0);
            hin = out;
        }
    } else {
        // fallback: proven atomic + fp32 path
        float* mct = (float*)d_ws;
        float* mcb = mct + (size_t)n_nodes * HDIM;
        const size_t mbytes = (size_t)n_nodes * HDIM * sizeof(float) * 2;
        const int agg_blocks_ct = (int)(((long long)n_edges_ct * 32 + 255) / 256);
        const int agg_blocks_cb = (int)(((long long)n_edges_cb * 32 + 255) / 256);
        const float* hcur = h0;
        for (int layer = 0; layer < 2; ++layer) {
            hipMemsetAsync(d_ws, 0, mbytes, stream);
            edge_agg_kernel<<<agg_blocks_ct, 256, 0, stream>>>(
                hcur, feat_ct, src_ct, dst_ct, mct, n_edges_ct);
            edge_agg_kernel<<<agg_blocks_cb, 256, 0, stream>>>(
                hcur, feat_cb, src_cb, dst_cb, mcb, n_edges_cb);
            gemm_gelu_res_kernel<<<256, 256, 0, stream>>>(
                mct, mcb, layer ? W1 : W0, layer ? b1 : b0, hcur, out, n_nodes);
            hcur = out;
        }
    }
}

// Round 12
// 279.054 us; speedup vs baseline: 1.2877x; 1.2877x over previous
//
#include <hip/hip_runtime.h>
#include <math.h>

#define HDIM 128
#define CH 4096                 // edges per partition chunk
typedef unsigned int uint;
using short8 = __attribute__((ext_vector_type(8))) short;
using f32x4  = __attribute__((ext_vector_type(4))) float;

__device__ __forceinline__ uint pack_bf16x2(float a, float b) {
    uint ua = __float_as_uint(a), ub = __float_as_uint(b);
    ua = (ua + 0x7fffu + ((ua >> 16) & 1u)) >> 16;
    ub = (ub + 0x7fffu + ((ub >> 16) & 1u)) & 0xffff0000u;
    return ua | ub;
}
__device__ __forceinline__ unsigned short pack_bf16(float a) {
    uint ua = __float_as_uint(a);
    return (unsigned short)((ua + 0x7fffu + ((ua >> 16) & 1u)) >> 16);
}

// ---- prep: h->hb bf16 row-major, W->Wt bf16, PLUS per-chunk bucket
// ---- histograms (independent work, fused as extra blocks) ------------------
__global__ __launch_bounds__(256) void prep_hist_kernel(
    const float* __restrict__ h, uint* __restrict__ hb, int n_pairs,
    const float* __restrict__ W0, const float* __restrict__ W1,
    unsigned short* __restrict__ Wt0, unsigned short* __restrict__ Wt1,
    int conv_blocks,
    const int* __restrict__ dst_ct, int* __restrict__ cntm_ct, int n_ct, int nv_ct,
    const int* __restrict__ dst_cb, int* __restrict__ cntm_cb, int n_cb, int nv_cb,
    int nbuckets)
{
    if ((int)blockIdx.x < conv_blocks) {
        const int total = n_pairs + 2 * 32768;
        for (int i = blockIdx.x * 256 + threadIdx.x; i < total;
             i += conv_blocks * 256) {
            if (i < n_pairs) {
                float2 v = reinterpret_cast<const float2*>(h)[i];
                hb[i] = pack_bf16x2(v.x, v.y);
            } else {
                int t = i - n_pairs;
                const float* W = (t < 32768) ? W0 : W1;
                unsigned short* Wt = (t < 32768) ? Wt0 : Wt1;
                int j = t & 32767;
                int c = j >> 8, k = j & 255;
                Wt[j] = pack_bf16(W[k * HDIM + c]);
            }
        }
        return;
    }
    // histogram blocks
    __shared__ int lh[512];
    const int hb_id = blockIdx.x - conv_blocks;
    const bool cb = (hb_id >= nv_ct);
    const int vb = cb ? hb_id - nv_ct : hb_id;
    const int* dst = cb ? dst_cb : dst_ct;
    int* cntm      = cb ? cntm_cb : cntm_ct;
    const int n  = cb ? n_cb : n_ct;
    const int NV = cb ? nv_cb : nv_ct;
    for (int j = threadIdx.x; j < 512; j += 256) lh[j] = 0;
    __syncthreads();
    const int e0 = vb << 12;
    const int e1 = min(n, e0 + CH);
    for (int i = e0 + threadIdx.x; i < e1; i += 256)
        atomicAdd(&lh[dst[i] >> 7], 1);
    __syncthreads();
    for (int j = threadIdx.x; j < nbuckets; j += 256)
        cntm[j * NV + vb] = lh[j];
}

// ---- scanA: within-bucket exclusive scan of chunk counts + bucket totals ---
__global__ __launch_bounds__(256) void scanA_kernel(
    int* __restrict__ cntm_ct, int* __restrict__ tot_ct, int nv_ct,
    int* __restrict__ cntm_cb, int* __restrict__ tot_cb, int nv_cb,
    int nbuckets)
{
    __shared__ int buf[256];
    const bool cb = ((int)blockIdx.x >= nbuckets);
    const int b = cb ? blockIdx.x - nbuckets : blockIdx.x;
    int* cntm = cb ? cntm_cb : cntm_ct;
    int* tot  = cb ? tot_cb : tot_ct;
    const int NV = cb ? nv_cb : nv_ct;
    const int t = threadIdx.x;
    int base = 0;
    for (int t0 = 0; t0 < NV; t0 += 256) {
        const int idx = t0 + t;
        const int v = (idx < NV) ? cntm[b * NV + idx] : 0;
        buf[t] = v;
        __syncthreads();
        #pragma unroll
        for (int off = 1; off < 256; off <<= 1) {
            int x = (t >= off) ? buf[t - off] : 0;
            __syncthreads();
            buf[t] += x;
            __syncthreads();
        }
        if (idx < NV) cntm[b * NV + idx] = base + buf[t] - v;   // exclusive
        base += buf[255];
        __syncthreads();
    }
    if (t == 0) tot[b] = base;
}

// ---- scanB: scan bucket totals -> bucket base offsets (incl. grand total) --
__global__ __launch_bounds__(1024) void scanB_kernel(
    const int* __restrict__ tot_ct, int* __restrict__ bkt_ct,
    const int* __restrict__ tot_cb, int* __restrict__ bkt_cb, int nbuckets)
{
    __shared__ int buf[1024];
    const int* tot = blockIdx.x ? tot_cb : tot_ct;
    int* bkt       = blockIdx.x ? bkt_cb : bkt_ct;
    const int t = threadIdx.x;
    const int v = (t < nbuckets) ? tot[t] : 0;
    buf[t] = v;
    __syncthreads();
    #pragma unroll
    for (int off = 1; off < 1024; off <<= 1) {
        int x = (t >= off) ? buf[t - off] : 0;
        __syncthreads();
        buf[t] += x;
        __syncthreads();
    }
    if (t < nbuckets) bkt[t] = buf[t] - v;
    if (t == nbuckets - 1) bkt[nbuckets] = buf[t];
}

// ---- stage 1: partition edges into 128-node buckets (LDS cursors) ----------
__global__ __launch_bounds__(256) void part_kernel(
    const int* __restrict__ dst_ct, const int* __restrict__ src_ct,
    const float* __restrict__ feat_ct, const int* __restrict__ off_ct,
    const int* __restrict__ bkt_ct, int2* __restrict__ ebkt_ct, int n_ct, int nv_ct,
    const int* __restrict__ dst_cb, const int* __restrict__ src_cb,
    const float* __restrict__ feat_cb, const int* __restrict__ off_cb,
    const int* __restrict__ bkt_cb, int2* __restrict__ ebkt_cb, int n_cb, int nv_cb,
    int nbuckets)
{
    __shared__ int cur[512];
    const bool cb = ((int)blockIdx.x >= nv_ct);
    const int vb = cb ? blockIdx.x - nv_ct : blockIdx.x;
    const int* dst    = cb ? dst_cb : dst_ct;
    const int* srcp   = cb ? src_cb : src_ct;
    const float* feat = cb ? feat_cb : feat_ct;
    const int* off    = cb ? off_cb : off_ct;
    const int* bkt    = cb ? bkt_cb : bkt_ct;
    int2* ebkt        = cb ? ebkt_cb : ebkt_ct;
    const int n  = cb ? n_cb : n_ct;
    const int NV = cb ? nv_cb : nv_ct;
    for (int j = threadIdx.x; j < nbuckets; j += 256)
        cur[j] = off[j * NV + vb] + bkt[j];
    __syncthreads();
    const int e0 = vb << 12;
    const int e1 = min(n, e0 + CH);
    for (int i = e0 + threadIdx.x; i < e1; i += 256) {
        int d = dst[i];
        int p = atomicAdd(&cur[d >> 7], 1);
        ebkt[p] = make_int2((srcp[i] & 0xFFFF) | ((d & 127) << 16),
                            __float_as_int(feat[i]));
    }
}

// ---- stage 2: within-bucket CSR sort + rowptr. Output records are 4B:
// ---- (feat_bf16 << 16) | src  -- dstLocal implied by CSR position. ---------
__global__ __launch_bounds__(256) void sortb_kernel(
    const int2* __restrict__ ebkt_ct, const int* __restrict__ bkt_ct,
    const int2* __restrict__ ebkt_cb, const int* __restrict__ bkt_cb,
    uint* __restrict__ ecsr_ct, uint* __restrict__ ecsr_cb,
    int* __restrict__ rowptr_ct, int* __restrict__ rowptr_cb,
    int n_nodes, int nbuckets)
{
    __shared__ int cnt[128];
    __shared__ int pref[128];
    const int b = blockIdx.x >> 1;
    const bool cb = blockIdx.x & 1;
    const int2* ebkt = cb ? ebkt_cb : ebkt_ct;
    const int* bkt   = cb ? bkt_cb : bkt_ct;
    uint* ecsr       = cb ? ecsr_cb : ecsr_ct;
    int* rowptr      = cb ? rowptr_cb : rowptr_ct;
    const int t = threadIdx.x;
    const int beg = bkt[b], end = bkt[b + 1];

    if (t < 128) cnt[t] = 0;
    __syncthreads();
    for (int i = beg + t; i < end; i += 256)
        atomicAdd(&cnt[((uint)ebkt[i].x) >> 16], 1);
    __syncthreads();
    if (t < 128) pref[t] = cnt[t];
    __syncthreads();
    #pragma unroll
    for (int off = 1; off < 128; off <<= 1) {
        int v = 0;
        if (t < 128 && t >= off) v = pref[t - off];
        __syncthreads();
        if (t < 128) pref[t] += v;
        __syncthreads();
    }
    if (t < 128) {
        int n0 = b * 128;
        int base = beg + pref[t] - cnt[t];
        if (n0 + t < n_nodes) rowptr[n0 + t] = base;
        cnt[t] = base;            // reuse as running cursor
    }
    if (b == nbuckets - 1 && t == 0) rowptr[n_nodes] = end;
    __syncthreads();
    for (int i = beg + t; i < end; i += 256) {
        int2 r = ebkt[i];
        int d = ((uint)r.x) >> 16;
        int p = atomicAdd(&cnt[d], 1);
        ecsr[p] = (uint)(r.x & 0xFFFF) |
                  ((uint)pack_bf16(__int_as_float(r.y)) << 16);
    }
}

// ------ Gather aggregation (proven R10 form): 2 edges/wave-step, uint2/lane -
__global__ __launch_bounds__(256) void csr_gather_bf16_kernel(
    const uint2* __restrict__ hb,
    const int* __restrict__ rp_ct, const uint* __restrict__ e_ct,
    const int* __restrict__ rp_cb, const uint* __restrict__ e_cb,
    uint2* __restrict__ mct, uint2* __restrict__ mcb, int n_nodes)
{
    const int lane = threadIdx.x & 63;
    const int half = lane >> 5;
    const int sub  = lane & 31;
    const int wave = (blockIdx.x * 256 + threadIdx.x) >> 6;
    const int nwaves = (gridDim.x * 256) >> 6;
    const int total = 2 * n_nodes;
    for (int v = wave; v < total; v += nwaves) {
        const bool cbt = (v >= n_nodes);
        const int n = cbt ? (v - n_nodes) : v;
        const int* rp    = cbt ? rp_cb : rp_ct;
        const uint* ecsr = cbt ? e_cb : e_ct;
        uint2* m = cbt ? mcb : mct;
        const int beg = rp[n], end = rp[n + 1];
        float a0 = 0.f, a1 = 0.f, a2 = 0.f, a3 = 0.f;
        for (int i0 = beg; i0 < end; i0 += 64) {
            const int cnt = min(64, end - i0);
            int s = 0; float f = 0.0f;
            if (lane < cnt) {
                uint e = ecsr[i0 + lane];
                s = (int)(e & 0xFFFFu);
                f = __uint_as_float(e & 0xffff0000u);
            }
            const int npair = (cnt + 1) >> 1;
            #pragma unroll 4
            for (int jj = 0; jj < npair; ++jj) {
                int idx = jj * 2 + half;     // lanes >= cnt carry f=0 (safe)
                int   sj = __shfl(s, idx);
                float fj = __shfl(f, idx);
                uint2 hv = hb[(size_t)sj * 32 + sub];
                a0 = fmaf(fj, __uint_as_float(hv.x << 16),         a0);
                a1 = fmaf(fj, __uint_as_float(hv.x & 0xffff0000u), a1);
                a2 = fmaf(fj, __uint_as_float(hv.y << 16),         a2);
                a3 = fmaf(fj, __uint_as_float(hv.y & 0xffff0000u), a3);
            }
        }
        a0 += __shfl_xor(a0, 32);
        a1 += __shfl_xor(a1, 32);
        a2 += __shfl_xor(a2, 32);
        a3 += __shfl_xor(a3, 32);
        if (half == 0)
            m[(size_t)n * 32 + sub] = make_uint2(pack_bf16x2(a0, a1),
                                                 pack_bf16x2(a2, a3));
    }
}

// -------- Zero-LDS MFMA GEMM with bf16-residual dataflow --------------------
// mode 0 (layer 1): residual from fp32 h_in; write ONLY hb_out (bf16).
// mode 1 (layer 2): residual from bf16 hb_in; write ONLY h_out (fp32).
__global__ __launch_bounds__(256) void gemm_mfma_kernel(
    const unsigned short* __restrict__ mct, const unsigned short* __restrict__ mcb,
    const unsigned short* __restrict__ Wt, const float* __restrict__ bias,
    const float* __restrict__ h_in, const unsigned short* __restrict__ hb_in,
    float* __restrict__ h_out, unsigned short* __restrict__ hb_out,
    int n_nodes, int mode)
{
    const int base = blockIdx.x * 128;
    const int lane = threadIdx.x & 63;
    const int wid  = threadIdx.x >> 6;
    const int lr = lane & 15, lg = lane >> 4;
    const int row0 = base + wid * 32;

    f32x4 acc[2][8];
    #pragma unroll
    for (int mi = 0; mi < 2; ++mi)
        #pragma unroll
        for (int ni = 0; ni < 8; ++ni)
            acc[mi][ni] = (f32x4){0.f, 0.f, 0.f, 0.f};

    const int last = (base + 128 > n_nodes);

    #pragma unroll
    for (int ks = 0; ks < 8; ++ks) {
        const int koff = ks * 32 + lg * 8;
        short8 a[2], b[8];
        #pragma unroll
        for (int mi = 0; mi < 2; ++mi) {
            int node = row0 + mi * 16 + lr;
            if (last && node >= n_nodes) node = n_nodes - 1;
            const unsigned short* srcp = (koff < 128)
                ? (mct + (size_t)node * HDIM + koff)
                : (mcb + (size_t)node * HDIM + (koff - 128));
            a[mi] = *reinterpret_cast<const short8*>(srcp);
        }
        #pragma unroll
        for (int ni = 0; ni < 8; ++ni) {
            int col = ni * 16 + lr;
            b[ni] = *reinterpret_cast<const short8*>(Wt + (size_t)col * 256 + koff);
        }
        #pragma unroll
        for (int mi = 0; mi < 2; ++mi)
            #pragma unroll
            for (int ni = 0; ni < 8; ++ni)
                acc[mi][ni] = __builtin_amdgcn_mfma_f32_16x16x32_bf16(
                    a[mi], b[ni], acc[mi][ni], 0, 0, 0);
    }

    #pragma unroll
    for (int mi = 0; mi < 2; ++mi) {
        #pragma unroll
        for (int ni = 0; ni < 8; ++ni) {
            const int col = ni * 16 + lr;
            const float bc = bias[col];
            #pragma unroll
            for (int j = 0; j < 4; ++j) {
                int node = row0 + mi * 16 + lg * 4 + j;
                if (node < n_nodes) {
                    float x = acc[mi][ni][j] + bc;
                    float g = 0.5f * x * (1.0f + erff(x * 0.70710678118654752f));
                    const size_t idx = (size_t)node * HDIM + col;
                    if (mode == 0) {
                        float o = h_in[idx] + g;
                        hb_out[idx] = pack_bf16(o);
                    } else {
                        float hprev = __uint_as_float((uint)hb_in[idx] << 16);
                        h_out[idx] = hprev + g;
                    }
                }
            }
        }
    }
}

// ---------------- Fallback path kernels (ws too small / big graphs) ---------
__global__ __launch_bounds__(256) void edge_agg_kernel(
    const float* __restrict__ h, const float* __restrict__ feat,
    const int* __restrict__ src, const int* __restrict__ dst,
    float* __restrict__ m, int n_edges)
{
    long long tid = (long long)blockIdx.x * 256 + threadIdx.x;
    int e = (int)(tid >> 5);
    if (e >= n_edges) return;
    int q = (int)(tid & 31);
    float f = feat[e];
    size_t s = (size_t)src[e] * HDIM;
    size_t d = (size_t)dst[e] * HDIM;
    float4 v = reinterpret_cast<const float4*>(h + s)[q];
    float* mp = m + d + (size_t)q * 4;
    unsafeAtomicAdd(mp + 0, f * v.x);
    unsafeAtomicAdd(mp + 1, f * v.y);
    unsafeAtomicAdd(mp + 2, f * v.z);
    unsafeAtomicAdd(mp + 3, f * v.w);
}

__global__ __launch_bounds__(256) void gemm_gelu_res_kernel(
    const float* __restrict__ mct, const float* __restrict__ mcb,
    const float* __restrict__ W, const float* __restrict__ bias,
    const float* __restrict__ h_in, float* __restrict__ h_out, int n_nodes)
{
    __shared__ float Wl[256 * HDIM];
    __shared__ float trow[8][2 * HDIM];
    for (int i = threadIdx.x; i < 256 * HDIM; i += 256)
        Wl[i] = W[i];
    const int c = threadIdx.x & 127;
    const int g = threadIdx.x >> 7;
    const float bc = bias[c];
    __syncthreads();
    const int niter = (n_nodes + 7) >> 3;
    for (int it = blockIdx.x; it < niter; it += gridDim.x) {
        __syncthreads();
        for (int j = threadIdx.x; j < 8 * 256; j += 256) {
            int nn = j >> 8;
            int k  = j & 255;
            long long node = (long long)it * 8 + nn;
            float val = 0.0f;
            if (node < n_nodes)
                val = (k < HDIM) ? mct[node * HDIM + k]
                                 : mcb[node * HDIM + (k - HDIM)];
            trow[nn][k] = val;
        }
        __syncthreads();
        const float* t0 = trow[g * 4 + 0];
        const float* t1 = trow[g * 4 + 1];
        const float* t2 = trow[g * 4 + 2];
        const float* t3 = trow[g * 4 + 3];
        float a0 = bc, a1 = bc, a2 = bc, a3 = bc;
        #pragma unroll 8
        for (int k = 0; k < 256; ++k) {
            float w = Wl[k * HDIM + c];
            a0 = fmaf(t0[k], w, a0);
            a1 = fmaf(t1[k], w, a1);
            a2 = fmaf(t2[k], w, a2);
            a3 = fmaf(t3[k], w, a3);
        }
        float accs[4] = {a0, a1, a2, a3};
        #pragma unroll
        for (int j = 0; j < 4; ++j) {
            long long node = (long long)it * 8 + g * 4 + j;
            if (node < n_nodes) {
                float x = accs[j];
                float gl = 0.5f * x * (1.0f + erff(x * 0.70710678118654752f));
                h_out[node * HDIM + c] = h_in[node * HDIM + c] + gl;
            }
        }
    }
}

extern "C" void kernel_launch(void* const* d_in, const int* in_sizes, int n_in,
                              void* d_out, int out_size, void* d_ws, size_t ws_size,
                              hipStream_t stream)
{
    const float* h0      = (const float*)d_in[0];
    const float* feat_ct = (const float*)d_in[1];
    const float* feat_cb = (const float*)d_in[2];
    const int*   src_ct  = (const int*)d_in[3];
    const int*   dst_ct  = (const int*)d_in[4];
    const int*   src_cb  = (const int*)d_in[5];
    const int*   dst_cb  = (const int*)d_in[6];
    const float* W0      = (const float*)d_in[7];
    const float* b0      = (const float*)d_in[8];
    const float* W1      = (const float*)d_in[9];
    const float* b1      = (const float*)d_in[10];

    const int n_nodes    = in_sizes[0] / HDIM;
    const int n_edges_ct = in_sizes[3];
    const int n_edges_cb = in_sizes[5];
    float* out = (float*)d_out;

    const int nbuckets = (n_nodes + 127) >> 7;
    const int nv_ct = (n_edges_ct + CH - 1) / CH;
    const int nv_cb = (n_edges_cb + CH - 1) / CH;

    // ---- workspace layout (256B-aligned chunks) ----
    char* p = (char*)d_ws;
    auto take = [&](size_t bytes) -> char* {
        char* r = p;
        p += (bytes + 255) & ~(size_t)255;
        return r;
    };
    unsigned short* hb   = (unsigned short*)take((size_t)n_nodes * HDIM * 2);
    unsigned short* mctb = (unsigned short*)take((size_t)n_nodes * HDIM * 2);
    unsigned short* mcbb = (unsigned short*)take((size_t)n_nodes * HDIM * 2);
    unsigned short* Wt0  = (unsigned short*)take(32768 * 2);
    unsigned short* Wt1  = (unsigned short*)take(32768 * 2);
    int* cntm_ct = (int*)take((size_t)nbuckets * nv_ct * 4);
    int* cntm_cb = (int*)take((size_t)nbuckets * nv_cb * 4);
    int* tot_ct  = (int*)take((size_t)nbuckets * 4);
    int* tot_cb  = (int*)take((size_t)nbuckets * 4);
    int* bkt_ct  = (int*)take(((size_t)nbuckets + 1) * 4);
    int* bkt_cb  = (int*)take(((size_t)nbuckets + 1) * 4);
    int* rowptr_ct = (int*)take(((size_t)n_nodes + 1) * 4);
    int* rowptr_cb = (int*)take(((size_t)n_nodes + 1) * 4);
    uint* ecsr_ct = (uint*)take((size_t)n_edges_ct * 4);
    uint* ecsr_cb = (uint*)take((size_t)n_edges_cb * 4);
    const size_t need_bytes = (size_t)(p - (char*)d_ws);
    // bucket-partition scratch overlaps mctb/mcbb (dead before gather writes m)
    int2* ebkt_ct = (int2*)mctb;
    int2* ebkt_cb = (int2*)mcbb;

    const bool ebkt_fits =
        ((size_t)n_edges_ct * 8 <= (size_t)n_nodes * HDIM * 2) &&
        ((size_t)n_edges_cb * 8 <= (size_t)n_nodes * HDIM * 2);

    if (ws_size >= need_bytes && n_nodes <= 65536 && ebkt_fits) {
        const int conv_blocks = 2048;
        prep_hist_kernel<<<conv_blocks + nv_ct + nv_cb, 256, 0, stream>>>(
            h0, (uint*)hb, n_nodes * (HDIM / 2), W0, W1, Wt0, Wt1, conv_blocks,
            dst_ct, cntm_ct, n_edges_ct, nv_ct,
            dst_cb, cntm_cb, n_edges_cb, nv_cb, nbuckets);
        scanA_kernel<<<nbuckets * 2, 256, 0, stream>>>(
            cntm_ct, tot_ct, nv_ct, cntm_cb, tot_cb, nv_cb, nbuckets);
        scanB_kernel<<<2, 1024, 0, stream>>>(
            tot_ct, bkt_ct, tot_cb, bkt_cb, nbuckets);
        part_kernel<<<nv_ct + nv_cb, 256, 0, stream>>>(
            dst_ct, src_ct, feat_ct, cntm_ct, bkt_ct, ebkt_ct, n_edges_ct, nv_ct,
            dst_cb, src_cb, feat_cb, cntm_cb, bkt_cb, ebkt_cb, n_edges_cb, nv_cb,
            nbuckets);
        sortb_kernel<<<nbuckets * 2, 256, 0, stream>>>(
            ebkt_ct, bkt_ct, ebkt_cb, bkt_cb, ecsr_ct, ecsr_cb,
            rowptr_ct, rowptr_cb, n_nodes, nbuckets);
        const int gemm_blocks = (n_nodes + 127) / 128;
        // layer 1: residual from fp32 h0 -> hb (bf16)
        csr_gather_bf16_kernel<<<2048, 256, 0, stream>>>(
            (const uint2*)hb, rowptr_ct, ecsr_ct, rowptr_cb, ecsr_cb,
            (uint2*)mctb, (uint2*)mcbb, n_nodes);
        gemm_mfma_kernel<<<gemm_blocks, 256, 0, stream>>>(
            mctb, mcbb, Wt0, b0, h0, hb, out, hb, n_nodes, 0);
        // layer 2: residual from bf16 hb -> fp32 out
        csr_gather_bf16_kernel<<<2048, 256, 0, stream>>>(
            (const uint2*)hb, rowptr_ct, ecsr_ct, rowptr_cb, ecsr_cb,
            (uint2*)mctb, (uint2*)mcbb, n_nodes);
        gemm_mfma_kernel<<<gemm_blocks, 256, 0, stream>>>(
            mctb, mcbb, Wt1, b1, h0, hb, out, hb, n_nodes, 1);
    } else {
        // fallback: proven atomic + fp32 path
        float* mct = (float*)d_ws;
        float* mcb = mct + (size_t)n_nodes * HDIM;
        const size_t mbytes = (size_t)n_nodes * HDIM * sizeof(float) * 2;
        const int agg_blocks_ct = (int)(((long long)n_edges_ct * 32 + 255) / 256);
        const int agg_blocks_cb = (int)(((long long)n_edges_cb * 32 + 255) / 256);
        const float* hcur = h0;
        for (int layer = 0; layer < 2; ++layer) {
            hipMemsetAsync(d_ws, 0, mbytes, stream);
            edge_agg_kernel<<<agg_blocks_ct, 256, 0, stream>>>(
                hcur, feat_ct, src_ct, dst_ct, mct, n_edges_ct);
            edge_agg_kernel<<<agg_blocks_cb, 256, 0, stream>>>(
                hcur, feat_cb, src_cb, dst_cb, mcb, n_edges_cb);
            gemm_gelu_res_kernel<<<256, 256, 0, stream>>>(
                mct, mcb, layer ? W1 : W0, layer ? b1 : b0, hcur, out, n_nodes);
            hcur = out;
        }
    }
}

// Round 13
// 259.167 us; speedup vs baseline: 1.3865x; 1.0767x over previous
//
#include <hip/hip_runtime.h>
#include <math.h>

#define HDIM 128
#define CH 4096                 // edges per partition chunk
typedef unsigned int uint;
using short8 = __attribute__((ext_vector_type(8))) short;
using f32x4  = __attribute__((ext_vector_type(4))) float;

__device__ __forceinline__ uint pack_bf16x2(float a, float b) {
    uint ua = __float_as_uint(a), ub = __float_as_uint(b);
    ua = (ua + 0x7fffu + ((ua >> 16) & 1u)) >> 16;
    ub = (ub + 0x7fffu + ((ub >> 16) & 1u)) & 0xffff0000u;
    return ua | ub;
}
__device__ __forceinline__ unsigned short pack_bf16(float a) {
    uint ua = __float_as_uint(a);
    return (unsigned short)((ua + 0x7fffu + ((ua >> 16) & 1u)) >> 16);
}

// ---- prep: h->hb bf16 row-major, W->Wt bf16, PLUS per-chunk bucket
// ---- histograms (independent work, fused as extra blocks) ------------------
__global__ __launch_bounds__(256) void prep_hist_kernel(
    const float* __restrict__ h, uint* __restrict__ hb, int n_pairs,
    const float* __restrict__ W0, const float* __restrict__ W1,
    unsigned short* __restrict__ Wt0, unsigned short* __restrict__ Wt1,
    int conv_blocks,
    const int* __restrict__ dst_ct, int* __restrict__ cntm_ct, int n_ct, int nv_ct,
    const int* __restrict__ dst_cb, int* __restrict__ cntm_cb, int n_cb, int nv_cb,
    int nbuckets)
{
    if ((int)blockIdx.x < conv_blocks) {
        const int total = n_pairs + 2 * 32768;
        for (int i = blockIdx.x * 256 + threadIdx.x; i < total;
             i += conv_blocks * 256) {
            if (i < n_pairs) {
                float2 v = reinterpret_cast<const float2*>(h)[i];
                hb[i] = pack_bf16x2(v.x, v.y);
            } else {
                int t = i - n_pairs;
                const float* W = (t < 32768) ? W0 : W1;
                unsigned short* Wt = (t < 32768) ? Wt0 : Wt1;
                int j = t & 32767;
                int c = j >> 8, k = j & 255;
                Wt[j] = pack_bf16(W[k * HDIM + c]);
            }
        }
        return;
    }
    // histogram blocks
    __shared__ int lh[512];
    const int hb_id = blockIdx.x - conv_blocks;
    const bool cb = (hb_id >= nv_ct);
    const int vb = cb ? hb_id - nv_ct : hb_id;
    const int* dst = cb ? dst_cb : dst_ct;
    int* cntm      = cb ? cntm_cb : cntm_ct;
    const int n  = cb ? n_cb : n_ct;
    const int NV = cb ? nv_cb : nv_ct;
    for (int j = threadIdx.x; j < 512; j += 256) lh[j] = 0;
    __syncthreads();
    const int e0 = vb << 12;
    const int e1 = min(n, e0 + CH);
    for (int i = e0 + threadIdx.x; i < e1; i += 256)
        atomicAdd(&lh[dst[i] >> 7], 1);
    __syncthreads();
    for (int j = threadIdx.x; j < nbuckets; j += 256)
        cntm[j * NV + vb] = lh[j];
}

// ---- scanA: within-bucket exclusive scan of chunk counts + bucket totals ---
__global__ __launch_bounds__(256) void scanA_kernel(
    int* __restrict__ cntm_ct, int* __restrict__ tot_ct, int nv_ct,
    int* __restrict__ cntm_cb, int* __restrict__ tot_cb, int nv_cb,
    int nbuckets)
{
    __shared__ int buf[256];
    const bool cb = ((int)blockIdx.x >= nbuckets);
    const int b = cb ? blockIdx.x - nbuckets : blockIdx.x;
    int* cntm = cb ? cntm_cb : cntm_ct;
    int* tot  = cb ? tot_cb : tot_ct;
    const int NV = cb ? nv_cb : nv_ct;
    const int t = threadIdx.x;
    int base = 0;
    for (int t0 = 0; t0 < NV; t0 += 256) {
        const int idx = t0 + t;
        const int v = (idx < NV) ? cntm[b * NV + idx] : 0;
        buf[t] = v;
        __syncthreads();
        #pragma unroll
        for (int off = 1; off < 256; off <<= 1) {
            int x = (t >= off) ? buf[t - off] : 0;
            __syncthreads();
            buf[t] += x;
            __syncthreads();
        }
        if (idx < NV) cntm[b * NV + idx] = base + buf[t] - v;   // exclusive
        base += buf[255];
        __syncthreads();
    }
    if (t == 0) tot[b] = base;
}

// ---- scanB: scan bucket totals -> bucket base offsets (incl. grand total) --
__global__ __launch_bounds__(1024) void scanB_kernel(
    const int* __restrict__ tot_ct, int* __restrict__ bkt_ct,
    const int* __restrict__ tot_cb, int* __restrict__ bkt_cb, int nbuckets)
{
    __shared__ int buf[1024];
    const int* tot = blockIdx.x ? tot_cb : tot_ct;
    int* bkt       = blockIdx.x ? bkt_cb : bkt_ct;
    const int t = threadIdx.x;
    const int v = (t < nbuckets) ? tot[t] : 0;
    buf[t] = v;
    __syncthreads();
    #pragma unroll
    for (int off = 1; off < 1024; off <<= 1) {
        int x = (t >= off) ? buf[t - off] : 0;
        __syncthreads();
        buf[t] += x;
        __syncthreads();
    }
    if (t < nbuckets) bkt[t] = buf[t] - v;
    if (t == nbuckets - 1) bkt[nbuckets] = buf[t];
}

// ---- stage 1: partition edges into 128-node buckets (LDS cursors) ----------
__global__ __launch_bounds__(256) void part_kernel(
    const int* __restrict__ dst_ct, const int* __restrict__ src_ct,
    const float* __restrict__ feat_ct, const int* __restrict__ off_ct,
    const int* __restrict__ bkt_ct, int2* __restrict__ ebkt_ct, int n_ct, int nv_ct,
    const int* __restrict__ dst_cb, const int* __restrict__ src_cb,
    const float* __restrict__ feat_cb, const int* __restrict__ off_cb,
    const int* __restrict__ bkt_cb, int2* __restrict__ ebkt_cb, int n_cb, int nv_cb,
    int nbuckets)
{
    __shared__ int cur[512];
    const bool cb = ((int)blockIdx.x >= nv_ct);
    const int vb = cb ? blockIdx.x - nv_ct : blockIdx.x;
    const int* dst    = cb ? dst_cb : dst_ct;
    const int* srcp   = cb ? src_cb : src_ct;
    const float* feat = cb ? feat_cb : feat_ct;
    const int* off    = cb ? off_cb : off_ct;
    const int* bkt    = cb ? bkt_cb : bkt_ct;
    int2* ebkt        = cb ? ebkt_cb : ebkt_ct;
    const int n  = cb ? n_cb : n_ct;
    const int NV = cb ? nv_cb : nv_ct;
    for (int j = threadIdx.x; j < nbuckets; j += 256)
        cur[j] = off[j * NV + vb] + bkt[j];
    __syncthreads();
    const int e0 = vb << 12;
    const int e1 = min(n, e0 + CH);
    for (int i = e0 + threadIdx.x; i < e1; i += 256) {
        int d = dst[i];
        int p = atomicAdd(&cur[d >> 7], 1);
        ebkt[p] = make_int2((srcp[i] & 0xFFFF) | ((d & 127) << 16),
                            __float_as_int(feat[i]));
    }
}

// ---- stage 2: within-bucket CSR sort + rowptr. Output records are 4B:
// ---- (feat_bf16 << 16) | src  -- dstLocal implied by CSR position. ---------
__global__ __launch_bounds__(256) void sortb_kernel(
    const int2* __restrict__ ebkt_ct, const int* __restrict__ bkt_ct,
    const int2* __restrict__ ebkt_cb, const int* __restrict__ bkt_cb,
    uint* __restrict__ ecsr_ct, uint* __restrict__ ecsr_cb,
    int* __restrict__ rowptr_ct, int* __restrict__ rowptr_cb,
    int n_nodes, int nbuckets)
{
    __shared__ int cnt[128];
    __shared__ int pref[128];
    const int b = blockIdx.x >> 1;
    const bool cb = blockIdx.x & 1;
    const int2* ebkt = cb ? ebkt_cb : ebkt_ct;
    const int* bkt   = cb ? bkt_cb : bkt_ct;
    uint* ecsr       = cb ? ecsr_cb : ecsr_ct;
    int* rowptr      = cb ? rowptr_cb : rowptr_ct;
    const int t = threadIdx.x;
    const int beg = bkt[b], end = bkt[b + 1];

    if (t < 128) cnt[t] = 0;
    __syncthreads();
    for (int i = beg + t; i < end; i += 256)
        atomicAdd(&cnt[((uint)ebkt[i].x) >> 16], 1);
    __syncthreads();
    if (t < 128) pref[t] = cnt[t];
    __syncthreads();
    #pragma unroll
    for (int off = 1; off < 128; off <<= 1) {
        int v = 0;
        if (t < 128 && t >= off) v = pref[t - off];
        __syncthreads();
        if (t < 128) pref[t] += v;
        __syncthreads();
    }
    if (t < 128) {
        int n0 = b * 128;
        int base = beg + pref[t] - cnt[t];
        if (n0 + t < n_nodes) rowptr[n0 + t] = base;
        cnt[t] = base;            // reuse as running cursor
    }
    if (b == nbuckets - 1 && t == 0) rowptr[n_nodes] = end;
    __syncthreads();
    for (int i = beg + t; i < end; i += 256) {
        int2 r = ebkt[i];
        int d = ((uint)r.x) >> 16;
        int p = atomicAdd(&cnt[d], 1);
        ecsr[p] = (uint)(r.x & 0xFFFF) |
                  ((uint)pack_bf16(__int_as_float(r.y)) << 16);
    }
}

// ------ Gather: 4 edges in flight per wave, 16 lanes x uint4 (16B) each -----
// One shfl per edge (packed 4B record broadcast, decoded locally). Reduce via
// shfl_xor(16,32); lanes 0-15 write one uint4 each -> full 256B row.
__global__ __launch_bounds__(256) void csr_gather_bf16_kernel(
    const uint4* __restrict__ hb,
    const int* __restrict__ rp_ct, const uint* __restrict__ e_ct,
    const int* __restrict__ rp_cb, const uint* __restrict__ e_cb,
    uint4* __restrict__ mct, uint4* __restrict__ mcb, int n_nodes)
{
    const int lane = threadIdx.x & 63;
    const int eg = lane >> 4;        // which edge of the quad
    const int q  = lane & 15;        // uint4 slot within the 256B row
    const int wave = (blockIdx.x * 256 + threadIdx.x) >> 6;
    const int nwaves = (gridDim.x * 256) >> 6;
    const int total = 2 * n_nodes;
    for (int v = wave; v < total; v += nwaves) {
        const bool cbt = (v >= n_nodes);
        const int n = cbt ? (v - n_nodes) : v;
        const int* rp    = cbt ? rp_cb : rp_ct;
        const uint* ecsr = cbt ? e_cb : e_ct;
        uint4* m = cbt ? mcb : mct;
        const int beg = rp[n], end = rp[n + 1];
        float a0 = 0.f, a1 = 0.f, a2 = 0.f, a3 = 0.f;
        float a4 = 0.f, a5 = 0.f, a6 = 0.f, a7 = 0.f;
        for (int i0 = beg; i0 < end; i0 += 64) {
            const int cnt = min(64, end - i0);
            uint e = 0;                       // src=0, feat=+0.0f for idle lanes
            if (lane < cnt) e = ecsr[i0 + lane];
            const int nquad = (cnt + 3) >> 2;
            #pragma unroll 4
            for (int jj = 0; jj < nquad; ++jj) {
                uint ej = __shfl(e, jj * 4 + eg);
                int   sj = (int)(ej & 0xFFFFu);
                float fj = __uint_as_float(ej & 0xffff0000u);
                uint4 hv = hb[(size_t)sj * 16 + q];
                a0 = fmaf(fj, __uint_as_float(hv.x << 16),         a0);
                a1 = fmaf(fj, __uint_as_float(hv.x & 0xffff0000u), a1);
                a2 = fmaf(fj, __uint_as_float(hv.y << 16),         a2);
                a3 = fmaf(fj, __uint_as_float(hv.y & 0xffff0000u), a3);
                a4 = fmaf(fj, __uint_as_float(hv.z << 16),         a4);
                a5 = fmaf(fj, __uint_as_float(hv.z & 0xffff0000u), a5);
                a6 = fmaf(fj, __uint_as_float(hv.w << 16),         a6);
                a7 = fmaf(fj, __uint_as_float(hv.w & 0xffff0000u), a7);
            }
        }
        a0 += __shfl_xor(a0, 16); a1 += __shfl_xor(a1, 16);
        a2 += __shfl_xor(a2, 16); a3 += __shfl_xor(a3, 16);
        a4 += __shfl_xor(a4, 16); a5 += __shfl_xor(a5, 16);
        a6 += __shfl_xor(a6, 16); a7 += __shfl_xor(a7, 16);
        a0 += __shfl_xor(a0, 32); a1 += __shfl_xor(a1, 32);
        a2 += __shfl_xor(a2, 32); a3 += __shfl_xor(a3, 32);
        a4 += __shfl_xor(a4, 32); a5 += __shfl_xor(a5, 32);
        a6 += __shfl_xor(a6, 32); a7 += __shfl_xor(a7, 32);
        if (eg == 0) {
            uint4 o;
            o.x = pack_bf16x2(a0, a1);
            o.y = pack_bf16x2(a2, a3);
            o.z = pack_bf16x2(a4, a5);
            o.w = pack_bf16x2(a6, a7);
            m[(size_t)n * 16 + q] = o;
        }
    }
}

// -------- Zero-LDS MFMA GEMM with bf16-residual dataflow --------------------
// mode 0 (layer 1): residual from fp32 h_in; write ONLY hb_out (bf16).
// mode 1 (layer 2): residual from bf16 hb_in; write ONLY h_out (fp32).
__global__ __launch_bounds__(256) void gemm_mfma_kernel(
    const unsigned short* __restrict__ mct, const unsigned short* __restrict__ mcb,
    const unsigned short* __restrict__ Wt, const float* __restrict__ bias,
    const float* __restrict__ h_in, const unsigned short* __restrict__ hb_in,
    float* __restrict__ h_out, unsigned short* __restrict__ hb_out,
    int n_nodes, int mode)
{
    const int base = blockIdx.x * 128;
    const int lane = threadIdx.x & 63;
    const int wid  = threadIdx.x >> 6;
    const int lr = lane & 15, lg = lane >> 4;
    const int row0 = base + wid * 32;

    f32x4 acc[2][8];
    #pragma unroll
    for (int mi = 0; mi < 2; ++mi)
        #pragma unroll
        for (int ni = 0; ni < 8; ++ni)
            acc[mi][ni] = (f32x4){0.f, 0.f, 0.f, 0.f};

    const int last = (base + 128 > n_nodes);

    #pragma unroll
    for (int ks = 0; ks < 8; ++ks) {
        const int koff = ks * 32 + lg * 8;
        short8 a[2], b[8];
        #pragma unroll
        for (int mi = 0; mi < 2; ++mi) {
            int node = row0 + mi * 16 + lr;
            if (last && node >= n_nodes) node = n_nodes - 1;
            const unsigned short* srcp = (koff < 128)
                ? (mct + (size_t)node * HDIM + koff)
                : (mcb + (size_t)node * HDIM + (koff - 128));
            a[mi] = *reinterpret_cast<const short8*>(srcp);
        }
        #pragma unroll
        for (int ni = 0; ni < 8; ++ni) {
            int col = ni * 16 + lr;
            b[ni] = *reinterpret_cast<const short8*>(Wt + (size_t)col * 256 + koff);
        }
        #pragma unroll
        for (int mi = 0; mi < 2; ++mi)
            #pragma unroll
            for (int ni = 0; ni < 8; ++ni)
                acc[mi][ni] = __builtin_amdgcn_mfma_f32_16x16x32_bf16(
                    a[mi], b[ni], acc[mi][ni], 0, 0, 0);
    }

    #pragma unroll
    for (int mi = 0; mi < 2; ++mi) {
        #pragma unroll
        for (int ni = 0; ni < 8; ++ni) {
            const int col = ni * 16 + lr;
            const float bc = bias[col];
            #pragma unroll
            for (int j = 0; j < 4; ++j) {
                int node = row0 + mi * 16 + lg * 4 + j;
                if (node < n_nodes) {
                    float x = acc[mi][ni][j] + bc;
                    float g = 0.5f * x * (1.0f + erff(x * 0.70710678118654752f));
                    const size_t idx = (size_t)node * HDIM + col;
                    if (mode == 0) {
                        float o = h_in[idx] + g;
                        hb_out[idx] = pack_bf16(o);
                    } else {
                        float hprev = __uint_as_float((uint)hb_in[idx] << 16);
                        h_out[idx] = hprev + g;
                    }
                }
            }
        }
    }
}

// ---------------- Fallback path kernels (ws too small / big graphs) ---------
__global__ __launch_bounds__(256) void edge_agg_kernel(
    const float* __restrict__ h, const float* __restrict__ feat,
    const int* __restrict__ src, const int* __restrict__ dst,
    float* __restrict__ m, int n_edges)
{
    long long tid = (long long)blockIdx.x * 256 + threadIdx.x;
    int e = (int)(tid >> 5);
    if (e >= n_edges) return;
    int q = (int)(tid & 31);
    float f = feat[e];
    size_t s = (size_t)src[e] * HDIM;
    size_t d = (size_t)dst[e] * HDIM;
    float4 v = reinterpret_cast<const float4*>(h + s)[q];
    float* mp = m + d + (size_t)q * 4;
    unsafeAtomicAdd(mp + 0, f * v.x);
    unsafeAtomicAdd(mp + 1, f * v.y);
    unsafeAtomicAdd(mp + 2, f * v.z);
    unsafeAtomicAdd(mp + 3, f * v.w);
}

__global__ __launch_bounds__(256) void gemm_gelu_res_kernel(
    const float* __restrict__ mct, const float* __restrict__ mcb,
    const float* __restrict__ W, const float* __restrict__ bias,
    const float* __restrict__ h_in, float* __restrict__ h_out, int n_nodes)
{
    __shared__ float Wl[256 * HDIM];
    __shared__ float trow[8][2 * HDIM];
    for (int i = threadIdx.x; i < 256 * HDIM; i += 256)
        Wl[i] = W[i];
    const int c = threadIdx.x & 127;
    const int g = threadIdx.x >> 7;
    const float bc = bias[c];
    __syncthreads();
    const int niter = (n_nodes + 7) >> 3;
    for (int it = blockIdx.x; it < niter; it += gridDim.x) {
        __syncthreads();
        for (int j = threadIdx.x; j < 8 * 256; j += 256) {
            int nn = j >> 8;
            int k  = j & 255;
            long long node = (long long)it * 8 + nn;
            float val = 0.0f;
            if (node < n_nodes)
                val = (k < HDIM) ? mct[node * HDIM + k]
                                 : mcb[node * HDIM + (k - HDIM)];
            trow[nn][k] = val;
        }
        __syncthreads();
        const float* t0 = trow[g * 4 + 0];
        const float* t1 = trow[g * 4 + 1];
        const float* t2 = trow[g * 4 + 2];
        const float* t3 = trow[g * 4 + 3];
        float a0 = bc, a1 = bc, a2 = bc, a3 = bc;
        #pragma unroll 8
        for (int k = 0; k < 256; ++k) {
            float w = Wl[k * HDIM + c];
            a0 = fmaf(t0[k], w, a0);
            a1 = fmaf(t1[k], w, a1);
            a2 = fmaf(t2[k], w, a2);
            a3 = fmaf(t3[k], w, a3);
        }
        float accs[4] = {a0, a1, a2, a3};
        #pragma unroll
        for (int j = 0; j < 4; ++j) {
            long long node = (long long)it * 8 + g * 4 + j;
            if (node < n_nodes) {
                float x = accs[j];
                float gl = 0.5f * x * (1.0f + erff(x * 0.70710678118654752f));
                h_out[node * HDIM + c] = h_in[node * HDIM + c] + gl;
            }
        }
    }
}

extern "C" void kernel_launch(void* const* d_in, const int* in_sizes, int n_in,
                              void* d_out, int out_size, void* d_ws, size_t ws_size,
                              hipStream_t stream)
{
    const float* h0      = (const float*)d_in[0];
    const float* feat_ct = (const float*)d_in[1];
    const float* feat_cb = (const float*)d_in[2];
    const int*   src_ct  = (const int*)d_in[3];
    const int*   dst_ct  = (const int*)d_in[4];
    const int*   src_cb  = (const int*)d_in[5];
    const int*   dst_cb  = (const int*)d_in[6];
    const float* W0      = (const float*)d_in[7];
    const float* b0      = (const float*)d_in[8];
    const float* W1      = (const float*)d_in[9];
    const float* b1      = (const float*)d_in[10];

    const int n_nodes    = in_sizes[0] / HDIM;
    const int n_edges_ct = in_sizes[3];
    const int n_edges_cb = in_sizes[5];
    float* out = (float*)d_out;

    const int nbuckets = (n_nodes + 127) >> 7;
    const int nv_ct = (n_edges_ct + CH - 1) / CH;
    const int nv_cb = (n_edges_cb + CH - 1) / CH;

    // ---- workspace layout (256B-aligned chunks) ----
    char* p = (char*)d_ws;
    auto take = [&](size_t bytes) -> char* {
        char* r = p;
        p += (bytes + 255) & ~(size_t)255;
        return r;
    };
    unsigned short* hb   = (unsigned short*)take((size_t)n_nodes * HDIM * 2);
    unsigned short* mctb = (unsigned short*)take((size_t)n_nodes * HDIM * 2);
    unsigned short* mcbb = (unsigned short*)take((size_t)n_nodes * HDIM * 2);
    unsigned short* Wt0  = (unsigned short*)take(32768 * 2);
    unsigned short* Wt1  = (unsigned short*)take(32768 * 2);
    int* cntm_ct = (int*)take((size_t)nbuckets * nv_ct * 4);
    int* cntm_cb = (int*)take((size_t)nbuckets * nv_cb * 4);
    int* tot_ct  = (int*)take((size_t)nbuckets * 4);
    int* tot_cb  = (int*)take((size_t)nbuckets * 4);
    int* bkt_ct  = (int*)take(((size_t)nbuckets + 1) * 4);
    int* bkt_cb  = (int*)take(((size_t)nbuckets + 1) * 4);
    int* rowptr_ct = (int*)take(((size_t)n_nodes + 1) * 4);
    int* rowptr_cb = (int*)take(((size_t)n_nodes + 1) * 4);
    uint* ecsr_ct = (uint*)take((size_t)n_edges_ct * 4);
    uint* ecsr_cb = (uint*)take((size_t)n_edges_cb * 4);
    const size_t need_bytes = (size_t)(p - (char*)d_ws);
    // bucket-partition scratch overlaps mctb/mcbb (dead before gather writes m)
    int2* ebkt_ct = (int2*)mctb;
    int2* ebkt_cb = (int2*)mcbb;

    const bool ebkt_fits =
        ((size_t)n_edges_ct * 8 <= (size_t)n_nodes * HDIM * 2) &&
        ((size_t)n_edges_cb * 8 <= (size_t)n_nodes * HDIM * 2);

    if (ws_size >= need_bytes && n_nodes <= 65536 && ebkt_fits) {
        const int conv_blocks = 2048;
        prep_hist_kernel<<<conv_blocks + nv_ct + nv_cb, 256, 0, stream>>>(
            h0, (uint*)hb, n_nodes * (HDIM / 2), W0, W1, Wt0, Wt1, conv_blocks,
            dst_ct, cntm_ct, n_edges_ct, nv_ct,
            dst_cb, cntm_cb, n_edges_cb, nv_cb, nbuckets);
        scanA_kernel<<<nbuckets * 2, 256, 0, stream>>>(
            cntm_ct, tot_ct, nv_ct, cntm_cb, tot_cb, nv_cb, nbuckets);
        scanB_kernel<<<2, 1024, 0, stream>>>(
            tot_ct, bkt_ct, tot_cb, bkt_cb, nbuckets);
        part_kernel<<<nv_ct + nv_cb, 256, 0, stream>>>(
            dst_ct, src_ct, feat_ct, cntm_ct, bkt_ct, ebkt_ct, n_edges_ct, nv_ct,
            dst_cb, src_cb, feat_cb, cntm_cb, bkt_cb, ebkt_cb, n_edges_cb, nv_cb,
            nbuckets);
        sortb_kernel<<<nbuckets * 2, 256, 0, stream>>>(
            ebkt_ct, bkt_ct, ebkt_cb, bkt_cb, ecsr_ct, ecsr_cb,
            rowptr_ct, rowptr_cb, n_nodes, nbuckets);
        const int gemm_blocks = (n_nodes + 127) / 128;
        // layer 1: residual from fp32 h0 -> hb (bf16)
        csr_gather_bf16_kernel<<<2048, 256, 0, stream>>>(
            (const uint4*)hb, rowptr_ct, ecsr_ct, rowptr_cb, ecsr_cb,
            (uint4*)mctb, (uint4*)mcbb, n_nodes);
        gemm_mfma_kernel<<<gemm_blocks, 256, 0, stream>>>(
            mctb, mcbb, Wt0, b0, h0, hb, out, hb, n_nodes, 0);
        // layer 2: residual from bf16 hb -> fp32 out
        csr_gather_bf16_kernel<<<2048, 256, 0, stream>>>(
            (const uint4*)hb, rowptr_ct, ecsr_ct, rowptr_cb, ecsr_cb,
            (uint4*)mctb, (uint4*)mcbb, n_nodes);
        gemm_mfma_kernel<<<gemm_blocks, 256, 0, stream>>>(
            mctb, mcbb, Wt1, b1, h0, hb, out, hb, n_nodes, 1);
    } else {
        // fallback: proven atomic + fp32 path
        float* mct = (float*)d_ws;
        float* mcb = mct + (size_t)n_nodes * HDIM;
        const size_t mbytes = (size_t)n_nodes * HDIM * sizeof(float) * 2;
        const int agg_blocks_ct = (int)(((long long)n_edges_ct * 32 + 255) / 256);
        const int agg_blocks_cb = (int)(((long long)n_edges_cb * 32 + 255) / 256);
        const float* hcur = h0;
        for (int layer = 0; layer < 2; ++layer) {
            hipMemsetAsync(d_ws, 0, mbytes, stream);
            edge_agg_kernel<<<agg_blocks_ct, 256, 0, stream>>>(
                hcur, feat_ct, src_ct, dst_ct, mct, n_edges_ct);
            edge_agg_kernel<<<agg_blocks_cb, 256, 0, stream>>>(
                hcur, feat_cb, src_cb, dst_cb, mcb, n_edges_cb);
            gemm_gelu_res_kernel<<<256, 256, 0, stream>>>(
                mct, mcb, layer ? W1 : W0, layer ? b1 : b0, hcur, out, n_nodes);
            hcur = out;
        }
    }
}